// Round 1
// baseline (368.454 us; speedup 1.0000x reference)
//
#include <hip/hip_runtime.h>
#include <math.h>

// SplashEncoding: 16-level hash grid, trilinear interp; levels 14/15 add
// Gaussian splash mixtures (ns=2/4) feeding both feature and GMM outputs.
//
// Config baked from reference:
//   res[i] = int(16 * 1.47**i)
//   levels 0..3 linear index (res^3 <= 2^17), 4..15 xor-prime hash mod 2^17
//   ns = {14: 2, 15: 4}; FDIM=2
//   FB row bases (rows of 2 floats), GB row bases (rows into means/stds)

#define HMASK 131071

__constant__ int c_res[16] = {16,23,34,50,74,109,161,237,348,512,753,1108,1629,2394,3520,5174};
__constant__ int c_fb[16]  = {0,4096,16263,55567,180567,311639,442711,573783,704855,835927,
                              966999,1098071,1229143,1360215,1491287,1753431};

__device__ __forceinline__ void corner_setup(int res, float cx, float cy, float cz,
                                             int& px, int& py, int& pz,
                                             float& fx, float& fy, float& fz)
{
    const float hi = (float)((double)res - 1.001);   // matches jnp.clip(res*c, 0, res-1.001)
    float x = fminf(fmaxf((float)res * cx, 0.0f), hi);
    float y = fminf(fmaxf((float)res * cy, 0.0f), hi);
    float z = fminf(fmaxf((float)res * cz, 0.0f), hi);
    px = (int)x; py = (int)y; pz = (int)z;           // x,y,z >= 0 so trunc == floor
    fx = x - (float)px; fy = y - (float)py; fz = z - (float)pz;
}

template<bool HASH>
__device__ __forceinline__ void plain_level(
    int n, int level, int res, int fbase,
    float cx, float cy, float cz,
    const float* __restrict__ feats, float* __restrict__ out)
{
    int px, py, pz; float fx, fy, fz;
    corner_setup(res, cx, cy, cz, px, py, pz, fx, fy, fz);

    int   idxs[8];
    float ws[8];
#pragma unroll
    for (int k = 0; k < 8; ++k) {
        const int ox = (k >> 2) & 1, oy = (k >> 1) & 1, oz = k & 1;
        const int ix = px + ox, iy = py + oy, iz = pz + oz;
        ws[k] = (ox ? fx : 1.0f - fx) * (oy ? fy : 1.0f - fy) * (oz ? fz : 1.0f - fz);
        if (HASH) {
            unsigned h = (unsigned)ix ^ ((unsigned)iy * 2654435761u) ^ ((unsigned)iz * 805459861u);
            idxs[k] = (int)(h & HMASK);
        } else {
            idxs[k] = ix + iy * res + iz * res * res;
        }
    }
    // batch the 8 gathers for memory-level parallelism
    float2 fv[8];
#pragma unroll
    for (int k = 0; k < 8; ++k)
        fv[k] = *(const float2*)(feats + (size_t)(fbase + idxs[k]) * 2);

    float a0 = 0.0f, a1 = 0.0f;
#pragma unroll
    for (int k = 0; k < 8; ++k) { a0 += ws[k] * fv[k].x; a1 += ws[k] * fv[k].y; }

    *(float2*)(out + (size_t)n * 32 + 2 * level) = make_float2(a0, a1);
}

template<int NS>
__device__ __forceinline__ void splash_level(
    int n, int level, int res, int fbase, int gbase,
    float cx, float cy, float cz,
    const float* __restrict__ feats, const float* __restrict__ means,
    const float* __restrict__ stds, float* __restrict__ out, float* __restrict__ gmm)
{
    int px, py, pz; float fx, fy, fz;
    corner_setup(res, cx, cy, cz, px, py, pz, fx, fy, fz);

    float a0 = 0.0f, a1 = 0.0f, ag = 0.0f;
#pragma unroll
    for (int k = 0; k < 8; ++k) {
        const int ox = (k >> 2) & 1, oy = (k >> 1) & 1, oz = k & 1;
        const int ix = px + ox, iy = py + oy, iz = pz + oz;
        const float w = (ox ? fx : 1.0f - fx) * (oy ? fy : 1.0f - fy) * (oz ? fz : 1.0f - fz);
        unsigned h = (unsigned)ix ^ ((unsigned)iy * 2654435761u) ^ ((unsigned)iz * 805459861u);
        const int idx = (int)(h & HMASK);
        const int grow = gbase + idx * NS;

        float mm[3 * NS], sv[NS], ff[2 * NS];
        if (NS == 4) {
            // means row group: 12 floats, 48B stride, 16B aligned (gbase*12B % 16 == 0)
            const float4* mp = (const float4*)(means + (size_t)grow * 3);
            float4 A = mp[0], B = mp[1], C = mp[2];
            mm[0]=A.x; mm[1]=A.y; mm[2]=A.z; mm[3]=A.w;
            mm[4]=B.x; mm[5]=B.y; mm[6]=B.z; mm[7]=B.w;
            mm[8]=C.x; mm[9]=C.y; mm[10]=C.z; mm[11]=C.w;
            float4 s4 = *(const float4*)(stds + grow);   // 16B aligned
            sv[0]=s4.x; sv[1]=s4.y; sv[2]=s4.z; sv[3]=s4.w;
        } else {
            const float2* mp = (const float2*)(means + (size_t)grow * 3);  // 8B aligned
            float2 A = mp[0], B = mp[1], C = mp[2];
            mm[0]=A.x; mm[1]=A.y; mm[2]=B.x; mm[3]=B.y; mm[4]=C.x; mm[5]=C.y;
            float2 s2v = *(const float2*)(stds + grow);
            sv[0]=s2v.x; sv[1]=s2v.y;
        }
        const float2* fp = (const float2*)(feats + (size_t)(fbase + idx * NS) * 2);  // 8B aligned
#pragma unroll
        for (int s = 0; s < NS; ++s) { float2 t = fp[s]; ff[2*s] = t.x; ff[2*s+1] = t.y; }

#pragma unroll
        for (int s = 0; s < NS; ++s) {
            const float dx = cx - mm[3*s], dy = cy - mm[3*s+1], dz = cz - mm[3*s+2];
            const float sva = fabsf(sv[s]);
            const float d2 = dx*dx + dy*dy + dz*dz;
            const float s2 = sva * sva;
            const float sq = d2 / (2.0f * s2 + 1e-7f);
            const float gw = expf(-sq) / (2.5066282746310002f * sva + 1e-7f);
            const float wg = w * gw;
            a0 += wg * ff[2*s];
            a1 += wg * ff[2*s+1];
            ag += wg * (d2 / s2);
        }
    }
    *(float2*)(out + (size_t)n * 32 + 2 * level) = make_float2(a0, a1);
    gmm[n * 2 + (level - 14)] = ag;
}

__global__ __launch_bounds__(256) void splash_enc(
    const float* __restrict__ coords, const float* __restrict__ feats,
    const float* __restrict__ means,  const float* __restrict__ stds,
    float* __restrict__ out, int N)
{
    const int n = blockIdx.x * 256 + threadIdx.x;
    if (n >= N) return;
    const int level = blockIdx.y;        // block-uniform -> no wave divergence

    const float cx = coords[3*n+0], cy = coords[3*n+1], cz = coords[3*n+2];
    const int res = c_res[level];
    const int fbase = c_fb[level];
    float* gmm = out + (size_t)N * 32;

    if (level < 4)        plain_level<false>(n, level, res, fbase, cx, cy, cz, feats, out);
    else if (level < 14)  plain_level<true >(n, level, res, fbase, cx, cy, cz, feats, out);
    else if (level == 14) splash_level<2>(n, level, res, fbase, /*gbase=*/0,      cx, cy, cz, feats, means, stds, out, gmm);
    else                  splash_level<4>(n, level, res, fbase, /*gbase=*/262144, cx, cy, cz, feats, means, stds, out, gmm);
}

extern "C" void kernel_launch(void* const* d_in, const int* in_sizes, int n_in,
                              void* d_out, int out_size, void* d_ws, size_t ws_size,
                              hipStream_t stream) {
    const float* coords = (const float*)d_in[0];
    const float* feats  = (const float*)d_in[1];
    const float* means  = (const float*)d_in[2];
    const float* stds   = (const float*)d_in[3];
    float* out = (float*)d_out;
    const int N = in_sizes[0] / 3;   // 262144

    dim3 grid((N + 255) / 256, 16);
    splash_enc<<<grid, dim3(256), 0, stream>>>(coords, feats, means, stds, out, N);
}